// Round 11
// baseline (84.565 us; speedup 1.0000x reference)
//
#include <hip/hip_runtime.h>
#include <hip/hip_bf16.h>

typedef _Float16 f16x8 __attribute__((ext_vector_type(8)));
typedef float f32x4 __attribute__((ext_vector_type(4)));

#define BB 8
#define NN 20
#define KK 5
#define DD 230
#define NQ 200

#define NB_TR 207     // transpose 230x230 -> Wt[230][232]
#define NB_B  200     // build B[320][160] f16 + epilogue table
#define NB_CONV 2300  // 575 M-tiles x 4 N-quarters
#define NB_FCB 480    // 2400 rows / 5 per block
#define NB_ATT 800
#define NB_CP 90      // 46000 float4 / 512

// ============ k_pre: fc_w transpose (padded) + im2col B build ============
__global__ void k_pre(const float* __restrict__ fc_w, float* __restrict__ Wt,
                      const float* __restrict__ w2, const float* __restrict__ b2,
                      const float* __restrict__ wf,
                      _Float16* __restrict__ Bglob, float2* __restrict__ tblg) {
    const int bid = blockIdx.x, tid = threadIdx.x;
    if (bid < NB_TR) {
        int idx = bid * 256 + tid;
        if (idx < DD * DD) {
            int i = idx / DD, j = idx - (idx / DD) * DD;
            Wt[j * 232 + i] = fc_w[idx];
        }
    } else {
        int g = (bid - NB_TR) * 256 + tid;   // < 51200 exactly
        int n = g / 160, k = g - n * 160;    // n in [0,320)
        int o = n / 5, i = n % 5;
        int c = k / 5, j = k - c * 5;
        int t = j - i + 2;
        float val = (t >= 0 && t < 5) ? w2[(o * 32 + c) * 5 + t] : 0.f;
        Bglob[g] = (_Float16)val;
        if (g < 320) {
            int o2 = g / 5, i2 = g % 5;
            tblg[g] = make_float2(b2[o2], wf[o2 * 5 + i2]);
        }
    }
}

// ============ k_main: conv-as-MFMA with reg-B (0..2299) + fc (2300..2779) ============
__global__ __launch_bounds__(320, 4)
void k_main(const float* __restrict__ S, const float* __restrict__ Q,
            const float* __restrict__ w1, const float* __restrict__ b1,
            const _Float16* __restrict__ Bglob, const float2* __restrict__ tblg,
            float* __restrict__ scp4,
            const float* __restrict__ Wt, const float* __restrict__ fc_b,
            float* __restrict__ Sf, float* __restrict__ Qf) {
    __shared__ __align__(16) _Float16 Xs[64 * 168];   // 21504 B
    __shared__ __align__(16) float xfp[5][64];        //  1280 B
    const int bid = blockIdx.x, tid = threadIdx.x;

    if (bid >= NB_CONV) {
        // ---- fc: 5 rows per block; thread = (row = tid>>6, cols = 4*lane) ----
        const int fb = bid - NB_CONV;
        const int lane = tid & 63;
        const int row = __builtin_amdgcn_readfirstlane(fb * 5 + (tid >> 6));
        const float* inp;
        float* outp;
        float scale;
        if (row < BB * NN * KK) {
            inp = S + (size_t)row * DD;
            outp = Sf + (size_t)row * DD;
            scale = 2.8853900817779268f;   // 2*log2(e)
        } else {
            int r = row - BB * NN * KK;
            inp = Q + (size_t)r * DD;
            outp = Qf + (size_t)r * DD;
            scale = 1.0f;
        }
        const int c0 = lane * 4;
        float a0 = 0.f, a1 = 0.f, a2 = 0.f, a3 = 0.f;
#pragma unroll 5
        for (int k = 0; k < DD; k++) {
            float4 w = *(const float4*)&Wt[k * 232 + c0];
            float s = inp[k];
            a0 = fmaf(s, w.x, a0);
            a1 = fmaf(s, w.y, a1);
            a2 = fmaf(s, w.z, a2);
            a3 = fmaf(s, w.w, a3);
        }
        float av[4] = {a0, a1, a2, a3};
#pragma unroll
        for (int j = 0; j < 4; j++) {
            int c = c0 + j;
            if (c < DD) outp[c] = (av[j] + fc_b[c]) * scale;
        }
        return;
    }

    // ---- conv unit: (Mb = 64 rows, q = 80 N-cols); wave w owns 16 cols ----
    const int q = bid & 3;
    const int Mb = bid >> 2;
    const int lane = tid & 63;
    const int w = __builtin_amdgcn_readfirstlane(tid >> 6);   // 0..4
    const int ncl = lane & 15;
    const int kg8 = (lane >> 4) * 8;
    const int ncol = q * 80 + w * 16 + ncl;   // global N col in [0,320)

    // B fragments in registers (L2-hot gather, once per block)
    f16x8 breg[5];
#pragma unroll
    for (int ks = 0; ks < 5; ks++)
        breg[ks] = *(const f16x8*)&Bglob[ncol * 160 + ks * 32 + kg8];
    const float2 bw = tblg[ncol];

    // conv1: rows = lane; channels c = w, w+5, ... (<32)
    {
        const int row = lane;
        const int m = Mb * 64 + row;
        const int img = m / DD;
        const int d = m - img * DD;
        const float* sp = S + (size_t)img * KK * DD + d;
        float in5[5];
#pragma unroll
        for (int j = 0; j < 5; j++) in5[j] = sp[j * DD];
        for (int c = w; c < 32; c += 5) {
            float wl[5];
#pragma unroll
            for (int t = 0; t < 5; t++) wl[t] = w1[c * 5 + t];
            float bb = b1[c];
#pragma unroll
            for (int i = 0; i < 5; i++) {
                float a = bb;
#pragma unroll
                for (int t = 0; t < 5; t++) {
                    int j = i + t - 2;
                    if (j >= 0 && j < 5) a = fmaf(wl[t], in5[j], a);
                }
                Xs[row * 168 + c * 5 + i] = (_Float16)fmaxf(a, 0.f);
            }
        }
    }
    __syncthreads();

    // MFMA: wave w covers all 64 M-rows (4 sub-tiles) x its 16 N-cols, K=160
#pragma unroll
    for (int ms = 0; ms < 4; ms++) {
        f32x4 a = {0.f, 0.f, 0.f, 0.f};
#pragma unroll
        for (int ks = 0; ks < 5; ks++) {
            f16x8 af = *(const f16x8*)&Xs[(ms * 16 + ncl) * 168 + ks * 32 + kg8];
            a = __builtin_amdgcn_mfma_f32_16x16x32_f16(af, breg[ks], a, 0, 0, 0);
        }
        // epilogue: relu(C + b2[o]) * wf[o,i], reduce over the 16 cols
        float v0 = fmaxf(a[0] + bw.x, 0.f) * bw.y;
        float v1 = fmaxf(a[1] + bw.x, 0.f) * bw.y;
        float v2 = fmaxf(a[2] + bw.x, 0.f) * bw.y;
        float v3 = fmaxf(a[3] + bw.x, 0.f) * bw.y;
#pragma unroll
        for (int off = 1; off < 16; off <<= 1) {
            v0 += __shfl_xor(v0, off, 64);
            v1 += __shfl_xor(v1, off, 64);
            v2 += __shfl_xor(v2, off, 64);
            v3 += __shfl_xor(v3, off, 64);
        }
        if (ncl == 0) {
            float4 vv = make_float4(v0, v1, v2, v3);
            *(float4*)&xfp[w][ms * 16 + (lane >> 4) * 4] = vv;
        }
    }
    __syncthreads();

    // cross-wave (over 5 waves = 80 cols) partial sum -> scp4[q][m]
    if (tid < 64) {
        float s = xfp[0][tid] + xfp[1][tid] + xfp[2][tid] + xfp[3][tid] + xfp[4][tid];
        scp4[(size_t)q * 36800 + Mb * 64 + tid] = s;
    }
}

// ============ k_att: att (0..799) + S-copy (800..889); 512 thr ============
__global__ __launch_bounds__(512)
void k_att(const float* __restrict__ Sf, const float* __restrict__ Qf,
           const float* __restrict__ S, const float* __restrict__ Q,
           const float* __restrict__ scp4, const float* __restrict__ convf_b,
           float* __restrict__ out, float* __restrict__ Scopy) {
    __shared__ float Sft[25][232];
    __shared__ float Ls[8][25];
    const int bid = blockIdx.x, tid = threadIdx.x;
    if (bid >= NB_ATT) {
        int g = (bid - NB_ATT) * 512 + tid;
        if (g < 46000) ((float4*)Scopy)[g] = ((const float4*)S)[g];
        return;
    }
    const int lane = tid & 63, wv = tid >> 6;   // wv 0..7
    const int qg = bid % 25;
    const int nq = (bid / 25) & 3;
    const int b  = bid / 100;
    const int q  = qg * 8 + wv, n0 = nq * 5;
    const float LOG2E = 1.4426950408889634f;
    const float bf0 = convf_b[0];

    const float* sfb = Sf + ((size_t)b * 100 + n0 * 5) * DD;
    for (int e = tid; e < 25 * DD; e += 512) Sft[e / DD][e % DD] = sfb[e];
    __syncthreads();

    float qf[4];
    const float* qfp = Qf + ((size_t)b * NQ + q) * DD;
#pragma unroll
    for (int i = 0; i < 4; i++) {
        int d = lane + 64 * i;
        qf[i] = (d < DD) ? qfp[d] : 0.f;
    }
    for (int idx = 0; idx < 25; idx++) {
        float racc = 0.f;
#pragma unroll
        for (int i = 0; i < 4; i++) {
            int d = lane + 64 * i;
            float s = (d < DD) ? Sft[idx][d] : 0.f;
            float e = __builtin_amdgcn_exp2f(s * qf[i]);
            racc += __builtin_amdgcn_rcpf(e + 1.f);
        }
#pragma unroll
        for (int off = 32; off > 0; off >>= 1) racc += __shfl_xor(racc, off, 64);
        if (lane == 0) Ls[wv][idx] = fmaf(-2.f, racc, 256.f);
    }

    float qr[4];
    const float* qp = Q + ((size_t)b * NQ + q) * DD;
#pragma unroll
    for (int i = 0; i < 4; i++) {
        int d = lane + 64 * i;
        qr[i] = (d < DD) ? qp[d] : 0.f;
    }
    for (int nl = 0; nl < 5; nl++) {
        const float* lp = Ls[wv] + nl * 5;
        float v0 = lp[0], v1 = lp[1], v2 = lp[2], v3 = lp[3], v4 = lp[4];
        float m = fmaxf(fmaxf(fmaxf(v0, v1), fmaxf(v2, v3)), v4);
        float e0 = __builtin_amdgcn_exp2f((v0 - m) * LOG2E);
        float e1 = __builtin_amdgcn_exp2f((v1 - m) * LOG2E);
        float e2 = __builtin_amdgcn_exp2f((v2 - m) * LOG2E);
        float e3 = __builtin_amdgcn_exp2f((v3 - m) * LOG2E);
        float e4 = __builtin_amdgcn_exp2f((v4 - m) * LOG2E);
        float inv = __builtin_amdgcn_rcpf(e0 + e1 + e2 + e3 + e4);
        float a0 = e0 * inv, a1 = e1 * inv, a2 = e2 * inv, a3 = e3 * inv, a4 = e4 * inv;
        const int n = n0 + nl;
        const float* spn = S + (size_t)(b * NN + n) * KK * DD;
        const float* s0 = scp4 + (size_t)(b * NN + n) * DD;
        float acc = 0.f;
#pragma unroll
        for (int i = 0; i < 4; i++) {
            int d = lane + 64 * i;
            if (d < DD) {
                float rep = a0 * spn[d] + a1 * spn[DD + d] + a2 * spn[2 * DD + d]
                          + a3 * spn[3 * DD + d] + a4 * spn[4 * DD + d];
                float df = rep - qr[i];
                float sw = s0[d] + s0[36800 + d] + s0[73600 + d] + s0[110400 + d];
                float scw = fmaxf(sw + bf0, 0.f) * 700.f;
                acc = fmaf(df * df, scw, acc);
            }
        }
#pragma unroll
        for (int off = 32; off > 0; off >>= 1) acc += __shfl_xor(acc, off, 64);
        if (lane == 0) out[((size_t)b * NQ + q) * NN + n] = -acc;
    }
}

extern "C" void kernel_launch(void* const* d_in, const int* in_sizes, int n_in,
                              void* d_out, int out_size, void* d_ws, size_t ws_size,
                              hipStream_t stream) {
    const float* S       = (const float*)d_in[0];
    const float* Q       = (const float*)d_in[1];
    const float* fc_w    = (const float*)d_in[2];
    const float* fc_b    = (const float*)d_in[3];
    const float* conv1_w = (const float*)d_in[4];
    const float* conv1_b = (const float*)d_in[5];
    const float* conv2_w = (const float*)d_in[6];
    const float* conv2_b = (const float*)d_in[7];
    const float* convf_w = (const float*)d_in[8];
    const float* convf_b = (const float*)d_in[9];
    float* out = (float*)d_out;

    float* ws = (float*)d_ws;
    float* Wt   = ws;                                  // 53824 dwords
    float* Sf   = Wt + 53824;                          // 184000
    float* Qf   = Sf + 184000;                         // 368000
    float* scp4 = Qf + 368000;                         // 147200 (4 quarters)
    _Float16* Bglob = (_Float16*)(scp4 + 147200);      // 25600 dwords
    float2* tblg = (float2*)(scp4 + 147200 + 25600);   // 640 dwords

    k_pre<<<NB_TR + NB_B, 256, 0, stream>>>(
        fc_w, Wt, conv2_w, conv2_b, convf_w, Bglob, tblg);
    k_main<<<NB_CONV + NB_FCB, 320, 0, stream>>>(
        S, Q, conv1_w, conv1_b, Bglob, tblg, scp4, Wt, fc_b, Sf, Qf);
    k_att<<<NB_ATT + NB_CP, 512, 0, stream>>>(
        Sf, Qf, S, Q, scp4, convf_b, out, out + (size_t)BB * NQ * NN);
}

// Round 12
// 74.250 us; speedup vs baseline: 1.1389x; 1.1389x over previous
//
#include <hip/hip_runtime.h>
#include <hip/hip_bf16.h>

typedef _Float16 f16x8 __attribute__((ext_vector_type(8)));
typedef float f32x4 __attribute__((ext_vector_type(4)));

#define BB 8
#define NN 20
#define KK 5
#define DD 230
#define NQ 200

#define NB_TR 207    // transpose 230x230 -> Wt[230][232]
#define NB_B  200    // build B[320][160] f16 + epilogue table
#define NB_CP 180    // 46000 float4 S-copy
#define NB_FC 60     // 2400 rows / 40 per block (5 waves x 8 rows)
#define NB_CONV 1150 // 575 M-tiles x 2 N-halves
#define NB_ATT 800

// ============ k_pre: fc_w transpose + im2col B build + S copy ============
__global__ void k_pre(const float* __restrict__ fc_w, float* __restrict__ Wt,
                      const float* __restrict__ w2, const float* __restrict__ b2,
                      const float* __restrict__ wf,
                      _Float16* __restrict__ Bglob, float2* __restrict__ tblg,
                      const float* __restrict__ S, float* __restrict__ Scopy) {
    const int bid = blockIdx.x, tid = threadIdx.x;
    if (bid < NB_TR) {
        int idx = bid * 256 + tid;
        if (idx < DD * DD) {
            int i = idx / DD, j = idx - (idx / DD) * DD;
            Wt[j * 232 + i] = fc_w[idx];
        }
    } else if (bid < NB_TR + NB_B) {
        int g = (bid - NB_TR) * 256 + tid;   // < 51200 exactly
        int n = g / 160, k = g - n * 160;    // n in [0,320)
        int o = n / 5, i = n % 5;
        int c = k / 5, j = k - c * 5;
        int t = j - i + 2;
        float val = (t >= 0 && t < 5) ? w2[(o * 32 + c) * 5 + t] : 0.f;
        Bglob[g] = (_Float16)val;
        if (g < 320) {
            int o2 = g / 5, i2 = g % 5;
            tblg[g] = make_float2(b2[o2], wf[o2 * 5 + i2]);
        }
    } else {
        int g = (bid - NB_TR - NB_B) * 256 + tid;
        if (g < 46000) ((float4*)Scopy)[g] = ((const float4*)S)[g];
    }
}

// ============ k_main: fc (0..59) + conv-as-MFMA swapped-operand (60..1209) ============
__global__ __launch_bounds__(320, 4)
void k_main(const float* __restrict__ S, const float* __restrict__ Q,
            const float* __restrict__ w1, const float* __restrict__ b1,
            const _Float16* __restrict__ Bglob, const float2* __restrict__ tblg,
            float* __restrict__ scp2,
            const float* __restrict__ Wt, const float* __restrict__ fc_b,
            float* __restrict__ Sf, float* __restrict__ Qf) {
    __shared__ __align__(16) _Float16 Xs[64 * 168];   // 21504 B
    __shared__ float xfp[5][64];                      //  1280 B
    const int bid = blockIdx.x, tid = threadIdx.x;
    const int lane = tid & 63;
    const int w = __builtin_amdgcn_readfirstlane(tid >> 6);   // 0..4 uniform

    if (bid < NB_FC) {
        // ---- fc: 8 rows per wave, 6-k chunks with explicit prefetch ----
        const int r0 = bid * 40 + w * 8;
        const float* inp;
        float* outp;
        float scale;
        if (r0 < BB * NN * KK) {
            inp = S + (size_t)r0 * DD;
            outp = Sf + (size_t)r0 * DD;
            scale = 2.8853900817779268f;   // 2*log2(e)
        } else {
            int r = r0 - BB * NN * KK;
            inp = Q + (size_t)r * DD;
            outp = Qf + (size_t)r * DD;
            scale = 1.0f;
        }
        const f32x4* WT4 = (const f32x4*)Wt;   // row stride 58 float4s
        f32x4 acc[8];
#pragma unroll
        for (int r = 0; r < 8; r++) acc[r] = (f32x4){0.f, 0.f, 0.f, 0.f};
        f32x4 wb[6], wn[6];
#pragma unroll
        for (int j = 0; j < 6; j++) wb[j] = WT4[j * 58 + lane];
        for (int ch = 0; ch < 38; ch++) {
            const int kn = (ch + 1) * 6;
            const int nload = (ch < 37) ? 6 : 2;
#pragma unroll
            for (int j = 0; j < 6; j++)
                if (j < nload) wn[j] = WT4[(kn + j) * 58 + lane];
#pragma unroll
            for (int j = 0; j < 6; j++) {
                const int k = ch * 6 + j;
#pragma unroll
                for (int r = 0; r < 8; r++)
                    acc[r] += inp[r * DD + k] * wb[j];
            }
#pragma unroll
            for (int j = 0; j < 6; j++) wb[j] = wn[j];
        }
#pragma unroll
        for (int j = 0; j < 2; j++) {
            const int k = 228 + j;
#pragma unroll
            for (int r = 0; r < 8; r++)
                acc[r] += inp[r * DD + k] * wb[j];
        }
        const int c0 = lane * 4;
#pragma unroll
        for (int r = 0; r < 8; r++)
#pragma unroll
            for (int jj = 0; jj < 4; jj++) {
                int c = c0 + jj;
                if (c < DD) outp[r * DD + c] = (acc[r][jj] + fc_b[c]) * scale;
            }
        return;
    }

    // ---- conv: Mb = 64 rows, half = 160 N-cols; wave w owns 32 n's ----
    const int bid2 = bid - NB_FC;
    const int Mb = bid2 >> 1;
    const int half = bid2 & 1;
    const int m0 = Mb * 64;

    // conv1 (2x redundant across halves): rows = lane, channels c = w,w+5,...
    {
        const int m = m0 + lane;
        const int img = m / DD;
        const int d = m - img * DD;
        const float* sp = S + (size_t)img * KK * DD + d;
        float in5[5];
#pragma unroll
        for (int j = 0; j < 5; j++) in5[j] = sp[j * DD];
        for (int c = w; c < 32; c += 5) {
            float wl[5];
#pragma unroll
            for (int t = 0; t < 5; t++) wl[t] = w1[c * 5 + t];
            float bb = b1[c];
#pragma unroll
            for (int i = 0; i < 5; i++) {
                float a = bb;
#pragma unroll
                for (int t = 0; t < 5; t++) {
                    int j = i + t - 2;
                    if (j >= 0 && j < 5) a = fmaf(wl[t], in5[j], a);
                }
                Xs[lane * 168 + c * 5 + i] = (_Float16)fmaxf(a, 0.f);
            }
        }
    }
    __syncthreads();

    const int ncl = lane & 15;
    const int kg8 = (lane >> 4) * 8;
    const int g4 = lane >> 4;
    float xf[4] = {0.f, 0.f, 0.f, 0.f};

#pragma unroll
    for (int nt = 0; nt < 2; nt++) {
        const int nb = half * 160 + w * 32 + nt * 16;
        f16x8 breg[5];
#pragma unroll
        for (int ks = 0; ks < 5; ks++)
            breg[ks] = *(const f16x8*)&Bglob[(nb + ncl) * 160 + ks * 32 + kg8];
        float2 tb[4];
#pragma unroll
        for (int r = 0; r < 4; r++) tb[r] = tblg[nb + g4 * 4 + r];
#pragma unroll
        for (int ms = 0; ms < 4; ms++) {
            f32x4 a = {0.f, 0.f, 0.f, 0.f};
#pragma unroll
            for (int ks = 0; ks < 5; ks++) {
                f16x8 af = *(const f16x8*)&Xs[(ms * 16 + ncl) * 168 + ks * 32 + kg8];
                a = __builtin_amdgcn_mfma_f32_16x16x32_f16(breg[ks], af, a, 0, 0, 0);
            }
            // D[n][m]: lane holds col m = ms*16+ncl, rows n = nb + g4*4 + r
#pragma unroll
            for (int r = 0; r < 4; r++)
                xf[ms] = fmaf(fmaxf(a[r] + tb[r].x, 0.f), tb[r].y, xf[ms]);
        }
    }
    // reduce over the 4 row-groups (lanes differing in bits 4-5)
#pragma unroll
    for (int ms = 0; ms < 4; ms++) {
        float v = xf[ms];
        v += __shfl_xor(v, 16, 64);
        v += __shfl_xor(v, 32, 64);
        xf[ms] = v;
    }
    if (lane < 16) {
#pragma unroll
        for (int ms = 0; ms < 4; ms++) xfp[w][ms * 16 + lane] = xf[ms];
    }
    __syncthreads();
    if (tid < 64) {
        float s = xfp[0][tid] + xfp[1][tid] + xfp[2][tid] + xfp[3][tid] + xfp[4][tid];
        scp2[(size_t)half * 36800 + m0 + tid] = s;
    }
}

// ============ k_att: 512 thr, wave per q; Sf tile in LDS ============
__global__ __launch_bounds__(512)
void k_att(const float* __restrict__ Sf, const float* __restrict__ Qf,
           const float* __restrict__ S, const float* __restrict__ Q,
           const float* __restrict__ scp2, const float* __restrict__ convf_b,
           float* __restrict__ out) {
    __shared__ float Sft[25][232];
    __shared__ float Ls[8][25];
    const int bid = blockIdx.x, tid = threadIdx.x;
    const int lane = tid & 63, wv = tid >> 6;   // wv 0..7
    const int qg = bid % 25;
    const int nq = (bid / 25) & 3;
    const int b  = bid / 100;
    const int q  = qg * 8 + wv, n0 = nq * 5;
    const float LOG2E = 1.4426950408889634f;
    const float bf0 = convf_b[0];

    const float* sfb = Sf + ((size_t)b * 100 + n0 * 5) * DD;
    for (int e = tid; e < 25 * DD; e += 512) Sft[e / DD][e % DD] = sfb[e];
    __syncthreads();

    float qf[4];
    const float* qfp = Qf + ((size_t)b * NQ + q) * DD;
#pragma unroll
    for (int i = 0; i < 4; i++) {
        int d = lane + 64 * i;
        qf[i] = (d < DD) ? qfp[d] : 0.f;
    }
    for (int idx = 0; idx < 25; idx++) {
        float racc = 0.f;
#pragma unroll
        for (int i = 0; i < 4; i++) {
            int d = lane + 64 * i;
            float s = (d < DD) ? Sft[idx][d] : 0.f;
            float e = __builtin_amdgcn_exp2f(s * qf[i]);
            racc += __builtin_amdgcn_rcpf(e + 1.f);
        }
#pragma unroll
        for (int off = 32; off > 0; off >>= 1) racc += __shfl_xor(racc, off, 64);
        if (lane == 0) Ls[wv][idx] = fmaf(-2.f, racc, 256.f);
    }

    float qr[4];
    const float* qp = Q + ((size_t)b * NQ + q) * DD;
#pragma unroll
    for (int i = 0; i < 4; i++) {
        int d = lane + 64 * i;
        qr[i] = (d < DD) ? qp[d] : 0.f;
    }
    for (int nl = 0; nl < 5; nl++) {
        const float* lp = Ls[wv] + nl * 5;
        float v0 = lp[0], v1 = lp[1], v2 = lp[2], v3 = lp[3], v4 = lp[4];
        float m = fmaxf(fmaxf(fmaxf(v0, v1), fmaxf(v2, v3)), v4);
        float e0 = __builtin_amdgcn_exp2f((v0 - m) * LOG2E);
        float e1 = __builtin_amdgcn_exp2f((v1 - m) * LOG2E);
        float e2 = __builtin_amdgcn_exp2f((v2 - m) * LOG2E);
        float e3 = __builtin_amdgcn_exp2f((v3 - m) * LOG2E);
        float e4 = __builtin_amdgcn_exp2f((v4 - m) * LOG2E);
        float inv = __builtin_amdgcn_rcpf(e0 + e1 + e2 + e3 + e4);
        float a0 = e0 * inv, a1 = e1 * inv, a2 = e2 * inv, a3 = e3 * inv, a4 = e4 * inv;
        const int n = n0 + nl;
        const float* spn = S + (size_t)(b * NN + n) * KK * DD;
        const float* s0 = scp2 + (size_t)(b * NN + n) * DD;
        float acc = 0.f;
#pragma unroll
        for (int i = 0; i < 4; i++) {
            int d = lane + 64 * i;
            if (d < DD) {
                float rep = a0 * spn[d] + a1 * spn[DD + d] + a2 * spn[2 * DD + d]
                          + a3 * spn[3 * DD + d] + a4 * spn[4 * DD + d];
                float df = rep - qr[i];
                float scw = fmaxf(s0[d] + s0[36800 + d] + bf0, 0.f) * 700.f;
                acc = fmaf(df * df, scw, acc);
            }
        }
#pragma unroll
        for (int off = 32; off > 0; off >>= 1) acc += __shfl_xor(acc, off, 64);
        if (lane == 0) out[((size_t)b * NQ + q) * NN + n] = -acc;
    }
}

extern "C" void kernel_launch(void* const* d_in, const int* in_sizes, int n_in,
                              void* d_out, int out_size, void* d_ws, size_t ws_size,
                              hipStream_t stream) {
    const float* S       = (const float*)d_in[0];
    const float* Q       = (const float*)d_in[1];
    const float* fc_w    = (const float*)d_in[2];
    const float* fc_b    = (const float*)d_in[3];
    const float* conv1_w = (const float*)d_in[4];
    const float* conv1_b = (const float*)d_in[5];
    const float* conv2_w = (const float*)d_in[6];
    const float* conv2_b = (const float*)d_in[7];
    const float* convf_w = (const float*)d_in[8];
    const float* convf_b = (const float*)d_in[9];
    float* out = (float*)d_out;

    float* ws = (float*)d_ws;
    float* Wt   = ws;                                  // 53824 dwords
    float* Sf   = Wt + 53824;                          // 184000
    float* Qf   = Sf + 184000;                         // 368000
    float* scp2 = Qf + 368000;                         // 73600 (2 halves)
    _Float16* Bglob = (_Float16*)(scp2 + 73600);       // 25600 dwords
    float2* tblg = (float2*)(scp2 + 73600 + 25600);    // 640 dwords

    k_pre<<<NB_TR + NB_B + NB_CP, 256, 0, stream>>>(
        fc_w, Wt, conv2_w, conv2_b, convf_w, Bglob, tblg,
        S, out + (size_t)BB * NQ * NN);
    k_main<<<NB_FC + NB_CONV, 320, 0, stream>>>(
        S, Q, conv1_w, conv1_b, Bglob, tblg, scp2, Wt, fc_b, Sf, Qf);
    k_att<<<NB_ATT, 512, 0, stream>>>(
        Sf, Qf, S, Q, scp2, convf_b, out);
}